// Round 1
// baseline (4549.947 us; speedup 1.0000x reference)
//
#include <hip/hip_runtime.h>
#include <cstdint>
#include <cstddef>

#define T_STEPS 64
#define XDIM 128
#define HDIM 1024
#define ORS 8192   /* out/input row stride = T*XD */

typedef __attribute__((ext_vector_type(8))) short short8;
typedef __attribute__((ext_vector_type(4))) float f32x4;

// pack geometry: gates B pack = [e][g=4][ks=36][nf=64][lane=64][j=8] bf16
static const size_t GSTRIDE = (size_t)36 * 64 * 64 * 8;  // shorts per group
static const size_t EPACK   = 4 * GSTRIDE;               // shorts per enc/dec

__device__ __forceinline__ short f2bf(float f) {
  union { float f; unsigned u; } c; c.f = f;
  unsigned u = c.u + (0x7fffu + ((c.u >> 16) & 1u));  // RNE; inputs finite
  return (short)(u >> 16);
}
__device__ __forceinline__ float sigm_(float x) { return 1.f / (1.f + __expf(-x)); }
__device__ __forceinline__ float tanh_(float x) { return 2.f / (1.f + __expf(-2.f * x)) - 1.f; }

__device__ __forceinline__ short8 cvt8(float4 a, float4 b) {
  short8 o;
  o[0] = f2bf(a.x); o[1] = f2bf(a.y); o[2] = f2bf(a.z); o[3] = f2bf(a.w);
  o[4] = f2bf(b.x); o[5] = f2bf(b.y); o[6] = f2bf(b.z); o[7] = f2bf(b.w);
  return o;
}
__device__ __forceinline__ float4 sc4(float s, float4 a) {
  return make_float4(s * a.x, s * a.y, s * a.z, s * a.w);
}
__device__ __forceinline__ float4 fma4(float s, float4 a, float4 c) {
  return make_float4(fmaf(s, a.x, c.x), fmaf(s, a.y, c.y), fmaf(s, a.z, c.z), fmaf(s, a.w, c.w));
}

// ---------------- prep kernels (run every call; deterministic) ----------------
__global__ __launch_bounds__(256) void pack_gates(
    const float* __restrict__ eWih, const float* __restrict__ eWhh,
    const float* __restrict__ dWih, const float* __restrict__ dWhh,
    short* __restrict__ Bg)
{
  unsigned t = blockIdx.x * 256u + threadIdx.x;   // 2*4*36*64*64 = 1,179,648
  unsigned l  = t & 63u; t >>= 6;
  unsigned nf = t & 63u; t >>= 6;
  unsigned ks = t % 36u; t /= 36u;
  unsigned g  = t & 3u;  t >>= 2;                 // t is now e (0=enc,1=dec)
  if (t >= 2u) return;
  if ((g == 2u && ks >= 4u) || (g == 3u && ks < 4u)) return;  // unused regions
  const float* Wih = t ? dWih : eWih;
  const float* Whh = t ? dWhh : eWhh;
  int k = (int)(ks * 32u + (l >> 4) * 8u);        // frag K offset for this lane
  int n = (int)(nf * 16u + (l & 15u));            // output column
  const float* src;
  if (g == 3u)      src = Whh + (size_t)(2048 + n) * HDIM + (k - XDIM); // h_n
  else if (g == 2u) src = Wih + (size_t)(2048 + n) * XDIM + k;          // i_n
  else if (ks < 4u) src = Wih + (size_t)(g * HDIM + n) * XDIM + k;      // r/z x-part
  else              src = Whh + (size_t)(g * HDIM + n) * HDIM + (k - XDIM);
  float4 a = *(const float4*)src;
  float4 b = *(const float4*)(src + 4);
  size_t off = ((((size_t)t * 4u + g) * 36u + ks) * 64u + nf) * 64u + l;
  *(short8*)(Bg + off * 8u) = cvt8(a, b);
}

__global__ __launch_bounds__(256) void pack_lin(const float* __restrict__ linW,
                                                short* __restrict__ Bl)
{
  unsigned t = blockIdx.x * 256u + threadIdx.x;   // 32*8*64 = 16384
  unsigned l  = t & 63u; t >>= 6;
  unsigned nf = t & 7u;  t >>= 3;
  unsigned ks = t;
  if (ks >= 32u) return;
  int k = (int)(ks * 32u + (l >> 4) * 8u);
  int n = (int)(nf * 16u + (l & 15u));
  const float* src = linW + (size_t)n * HDIM + k;
  float4 a = *(const float4*)src;
  float4 b = *(const float4*)(src + 4);
  size_t off = (((size_t)ks * 8u + nf) * 64u + l) * 8u;
  *(short8*)(Bl + off) = cvt8(a, b);
}

__global__ __launch_bounds__(256) void pack_bias(
    const float* __restrict__ eIh, const float* __restrict__ eHh,
    const float* __restrict__ dIh, const float* __restrict__ dHh,
    float* __restrict__ bias)  // [2][4][1024]
{
  unsigned t = blockIdx.x * 256u + threadIdx.x;   // 8192
  if (t >= 8192u) return;
  unsigned n = t & 1023u, g = (t >> 10) & 3u, e = t >> 12;
  const float* bih = e ? dIh : eIh;
  const float* bhh = e ? dHh : eHh;
  float v;
  if (g == 0u)      v = bih[n] + bhh[n];
  else if (g == 1u) v = bih[HDIM + n] + bhh[HDIM + n];
  else if (g == 2u) v = bih[2 * HDIM + n];
  else              v = bhh[2 * HDIM + n];
  bias[t] = v;
}

// ---------------- fused GRU-cell (+optional proj) kernel ----------------
// gates blocks: bid = mtile*16 + nslice  (8 mtiles x 16 nslices = 128 blocks, BM=32)
// proj blocks : pb  = bid - gatesBlocks  (4 mtiles x 2 ntiles = 8 blocks, BM=64)
__global__ __launch_bounds__(256) void rae_cell(
    const float* __restrict__ xs, int xon,
    const float* __restrict__ hA, float sA,
    const float* __restrict__ hB, float sB,
    const short* __restrict__ Bg, const float* __restrict__ bias,
    float* __restrict__ hOut,
    const float* __restrict__ pA, float pSA,
    const float* __restrict__ pB, float pSB,
    const short* __restrict__ Blin, const float* __restrict__ linb,
    float* __restrict__ outp, int gatesBlocks)
{
  const int tid  = threadIdx.x;
  const int lane = tid & 63;
  const int wave = tid >> 6;
  const int l15  = lane & 15, lq = lane >> 4;
  const int wm   = wave & 1,  wn = wave >> 1;
  const int bid  = blockIdx.x;

  if (bid < gatesBlocks) {
    const int mtile  = bid >> 4;
    const int nslice = bid & 15;
    const int arow   = mtile * 32 + wm * 16 + l15;
    const int nfbase = nslice * 4 + wn * 2;

    f32x4 acc[4][2];
    const f32x4 zero = {0.f, 0.f, 0.f, 0.f};
#pragma unroll
    for (int g = 0; g < 4; ++g) { acc[g][0] = zero; acc[g][1] = zero; }

    // ---- K part 1: x (k = 0..127), groups r,z,i_n ----
    if (xon) {
      const float* xr = xs + (size_t)arow * ORS;
#pragma unroll
      for (int ks = 0; ks < 4; ++ks) {
        const int kc = ks * 32 + lq * 8;
        short8 a = cvt8(*(const float4*)(xr + kc), *(const float4*)(xr + kc + 4));
#pragma unroll
        for (int g = 0; g < 3; ++g) {
          const short* bp = Bg + (size_t)g * GSTRIDE + (((size_t)ks * 64 + nfbase) * 64 + lane) * 8;
          short8 b0 = *(const short8*)bp;
          short8 b1 = *(const short8*)(bp + 512);
          acc[g][0] = __builtin_amdgcn_mfma_f32_16x16x32_bf16(a, b0, acc[g][0], 0, 0, 0);
          acc[g][1] = __builtin_amdgcn_mfma_f32_16x16x32_bf16(a, b1, acc[g][1], 0, 0, 0);
        }
      }
    }

    // ---- K part 2: h_prev = sA*hA + sB*hB (k = 128..1151), groups r,z,h_n ----
    const bool haveA = (sA != 0.f), haveB = (sB != 0.f);
    if (haveA || haveB) {
      const float* ha = hA + (size_t)arow * HDIM;
      const float* hb = hB + (size_t)arow * HDIM;
      for (int ks = 4; ks < 36; ++ks) {
        const int kc = (ks - 4) * 32 + lq * 8;
        float4 v0, v1;
        if (haveA) { v0 = sc4(sA, *(const float4*)(ha + kc)); v1 = sc4(sA, *(const float4*)(ha + kc + 4)); }
        else       { v0 = make_float4(0.f, 0.f, 0.f, 0.f); v1 = v0; }
        if (haveB) { v0 = fma4(sB, *(const float4*)(hb + kc), v0); v1 = fma4(sB, *(const float4*)(hb + kc + 4), v1); }
        short8 a = cvt8(v0, v1);
#pragma unroll
        for (int gi = 0; gi < 3; ++gi) {
          const int g = (gi < 2) ? gi : 3;
          const short* bp = Bg + (size_t)g * GSTRIDE + (((size_t)ks * 64 + nfbase) * 64 + lane) * 8;
          short8 b0 = *(const short8*)bp;
          short8 b1 = *(const short8*)(bp + 512);
          acc[g][0] = __builtin_amdgcn_mfma_f32_16x16x32_bf16(a, b0, acc[g][0], 0, 0, 0);
          acc[g][1] = __builtin_amdgcn_mfma_f32_16x16x32_bf16(a, b1, acc[g][1], 0, 0, 0);
        }
      }
    }

    // ---- epilogue: GRU pointwise, write h_new ----
#pragma unroll
    for (int nn = 0; nn < 2; ++nn) {
      const int col = nslice * 64 + wn * 32 + nn * 16 + l15;
      const float br = bias[col],            bz = bias[HDIM + col];
      const float bi = bias[2 * HDIM + col], bh = bias[3 * HDIM + col];
#pragma unroll
      for (int q = 0; q < 4; ++q) {
        const int row = mtile * 32 + wm * 16 + lq * 4 + q;
        const float r  = sigm_(acc[0][nn][q] + br);
        const float z  = sigm_(acc[1][nn][q] + bz);
        const float nv = tanh_(acc[2][nn][q] + bi + r * (acc[3][nn][q] + bh));
        float hp = 0.f;
        if (sA != 0.f) hp = sA * hA[(size_t)row * HDIM + col];
        if (sB != 0.f) hp = fmaf(sB, hB[(size_t)row * HDIM + col], hp);
        hOut[(size_t)row * HDIM + col] = (1.f - z) * nv + z * hp;
      }
    }
  } else {
    // ---- proj: out = (pSA*pA + pSB*pB) @ linW^T + linb ----
    const int pb_   = bid - gatesBlocks;
    const int mtile = pb_ >> 1, ntile = pb_ & 1;
    const int arow  = mtile * 64 + wm * 32 + l15;
    const int nfbase = ntile * 4 + wn * 2;
    f32x4 acc[2][2];
    const f32x4 zero = {0.f, 0.f, 0.f, 0.f};
    acc[0][0] = zero; acc[0][1] = zero; acc[1][0] = zero; acc[1][1] = zero;
    const bool haveB = (pSB != 0.f);
    const float* pa0 = pA + (size_t)arow * HDIM;
    const float* pa1 = pa0 + 16 * HDIM;
    const float* pb0 = pB + (size_t)arow * HDIM;
    const float* pb1 = pb0 + 16 * HDIM;
    for (int ks = 0; ks < 32; ++ks) {
      const int kc = ks * 32 + lq * 8;
      float4 v0 = sc4(pSA, *(const float4*)(pa0 + kc));
      float4 v1 = sc4(pSA, *(const float4*)(pa0 + kc + 4));
      float4 w0 = sc4(pSA, *(const float4*)(pa1 + kc));
      float4 w1 = sc4(pSA, *(const float4*)(pa1 + kc + 4));
      if (haveB) {
        v0 = fma4(pSB, *(const float4*)(pb0 + kc), v0);
        v1 = fma4(pSB, *(const float4*)(pb0 + kc + 4), v1);
        w0 = fma4(pSB, *(const float4*)(pb1 + kc), w0);
        w1 = fma4(pSB, *(const float4*)(pb1 + kc + 4), w1);
      }
      short8 a0 = cvt8(v0, v1);
      short8 a1 = cvt8(w0, w1);
#pragma unroll
      for (int nn = 0; nn < 2; ++nn) {
        const short* bp = Blin + (((size_t)ks * 8 + nfbase + nn) * 64 + lane) * 8;
        short8 b = *(const short8*)bp;
        acc[0][nn] = __builtin_amdgcn_mfma_f32_16x16x32_bf16(a0, b, acc[0][nn], 0, 0, 0);
        acc[1][nn] = __builtin_amdgcn_mfma_f32_16x16x32_bf16(a1, b, acc[1][nn], 0, 0, 0);
      }
    }
#pragma unroll
    for (int fm = 0; fm < 2; ++fm) {
#pragma unroll
      for (int nn = 0; nn < 2; ++nn) {
        const int col = ntile * 64 + wn * 32 + nn * 16 + l15;
        const float lb = linb[col];
#pragma unroll
        for (int q = 0; q < 4; ++q) {
          const int row = mtile * 64 + wm * 32 + fm * 16 + lq * 4 + q;
          outp[(size_t)row * ORS + col] = acc[fm][nn][q] + lb;
        }
      }
    }
  }
}

// ---------------- host: numpy-legacy MT19937 mask replication ----------------
static void compute_masks(float ew[64][2], float dw[64][2]) {
  unsigned mt[624];
  mt[0] = 0u;  // RandomState(0) -> init_genrand(0)
  for (int i = 1; i < 624; ++i)
    mt[i] = 1812433253u * (mt[i - 1] ^ (mt[i - 1] >> 30)) + (unsigned)i;
  int mti = 624;
  auto gen = [&]() -> unsigned {
    if (mti >= 624) {
      for (int i = 0; i < 624; ++i) {
        unsigned y = (mt[i] & 0x80000000u) | (mt[(i + 1) % 624] & 0x7fffffffu);
        unsigned v = mt[(i + 397) % 624] ^ (y >> 1);
        mt[i] = (y & 1u) ? (v ^ 0x9908b0dfu) : v;
      }
      mti = 0;
    }
    unsigned y = mt[mti++];
    y ^= y >> 11;
    y ^= (y << 7) & 0x9d2c5680u;
    y ^= (y << 15) & 0xefc60000u;
    y ^= y >> 18;
    return y;
  };
  // legacy randint(0,2): one 32-bit draw, low bit (masked rejection, mask=1)
  auto rbit = [&]() -> int { return (int)(gen() & 1u); };
  for (int t = 0; t < 64; ++t) {
    int w1 = rbit(); int w2 = (w1 == 0) ? 1 : rbit();
    ew[t][0] = (float)w1; ew[t][1] = (float)w2;
  }
  for (int t = 0; t < 64; ++t) {
    int w1 = rbit(); int w2 = (w1 == 0) ? 1 : rbit();
    dw[t][0] = (float)w1; dw[t][1] = (float)w2;
  }
}

extern "C" void kernel_launch(void* const* d_in, const int* in_sizes, int n_in,
                              void* d_out, int out_size, void* d_ws, size_t ws_size,
                              hipStream_t stream)
{
  const float* input = (const float*)d_in[0];
  const float* eWih = (const float*)d_in[1];
  const float* eWhh = (const float*)d_in[2];
  const float* eBih = (const float*)d_in[3];
  const float* eBhh = (const float*)d_in[4];
  const float* dWih = (const float*)d_in[5];
  const float* dWhh = (const float*)d_in[6];
  const float* dBih = (const float*)d_in[7];
  const float* dBhh = (const float*)d_in[8];
  const float* linW = (const float*)d_in[9];
  const float* linb = (const float*)d_in[10];
  float* out = (float*)d_out;

  // workspace layout
  //  BgE  : 4,718,592 bf16  (9,437,184 B)
  //  BgD  : 4,718,592 bf16  (9,437,184 B)
  //  Blin :   131,072 bf16  (  262,144 B)
  //  bias :     8,192 f32   (   32,768 B)
  //  hring: 16 x 256x1024 f32 (16,777,216 B)        total 35,946,496 B
  if (ws_size < 35946496u) return;
  char* ws = (char*)d_ws;
  short* BgE  = (short*)ws;
  short* BgD  = BgE + EPACK;
  short* Blin = (short*)(ws + 18874368u);
  float* bias = (float*)(ws + 19136512u);
  float* hring = (float*)(ws + 19169280u);

  float ew[64][2], dw[64][2];
  compute_masks(ew, dw);

  pack_gates<<<4608, 256, 0, stream>>>(eWih, eWhh, dWih, dWhh, BgE);
  pack_lin<<<64, 256, 0, stream>>>(linW, Blin);
  pack_bias<<<32, 256, 0, stream>>>(eBih, eBhh, dBih, dBhh, bias);

  auto slot = [&](int s) -> float* { return hring + (size_t)(s & 15) * (256 * HDIM); };

  // ---- encoder: 64 steps ----
  for (int i = 0; i < 64; ++i) {
    const float* hA = slot(i > 0 ? i - 1 : 0);
    float sA = (i == 0) ? 0.f : ew[i][0];
    const float* hB; float sB;
    if (i == 3)       { hB = slot(1);      sB = ew[i][1]; }   // list-wrap quirk
    else if (i == 4)  { hB = slot(3);      sB = ew[i][1]; }
    else if (i >= 10) { hB = slot(i - 10); sB = ew[i][1]; }
    else              { hB = slot(0);      sB = 0.f; }        // skip source is zeros
    rae_cell<<<128, 256, 0, stream>>>(
        input + (size_t)i * XDIM, 1,
        hA, sA, hB, sB, BgE, bias, slot(i),
        slot(0), 0.f, slot(0), 0.f, Blin, linb, out, 128);
  }

  // ---- decoder: 64 steps (h_enc = 2*h63 folded into scales) ----
  for (int i = 0; i < 64; ++i) {
    const float* hA; float sA;
    if (i == 0) { hA = slot(15); sA = 2.f * dw[0][0]; }
    else        { hA = slot(i - 1); sA = dw[i][0]; }
    const float* hB; float sB;
    if (i == 3)       { hB = slot(1);      sB = dw[i][1]; }
    else if (i == 4)  { hB = slot(3);      sB = dw[i][1]; }
    else if (i >= 10) { hB = slot(i - 10); sB = dw[i][1]; }
    else              { hB = slot(0);      sB = 0.f; }

    const float* xp = (i == 0) ? out : out + (size_t)(i - 1) * XDIM;
    int xon = (i == 0) ? 0 : 1;

    // proj_i = (h_{i-1} + skipB_i) @ linW^T + linb ; skipB_4 = h_4 -> separate launch
    const float* pA = (i == 0) ? slot(15) : slot(i - 1);
    float pSA = (i == 0) ? 2.f : 1.f;
    const float* pB; float pSB;
    if (i == 2)       { pB = slot(0);      pSB = 1.f; }
    else if (i == 3)  { pB = slot(2);      pSB = 1.f; }
    else if (i >= 10) { pB = slot(i - 10); pSB = 1.f; }
    else              { pB = slot(0);      pSB = 0.f; }  // i=0,1,5..9 (and i=4 dummy)

    int grid = (i == 4) ? 128 : 136;
    rae_cell<<<grid, 256, 0, stream>>>(
        xp, xon,
        hA, sA, hB, sB, BgD, bias + 4096, slot(i),
        pA, pSA, pB, pSB, Blin, linb, out + (size_t)i * XDIM, 128);

    if (i == 4) {  // proj_4 needs h_4 (written by the launch above)
      rae_cell<<<8, 256, 0, stream>>>(
          xp, 0,
          hA, 0.f, hB, 0.f, BgD, bias + 4096, slot(0),
          slot(3), 1.f, slot(4), 1.f, Blin, linb, out + (size_t)4 * XDIM, 0);
    }
  }
}

// Round 2
// 1344.005 us; speedup vs baseline: 3.3854x; 3.3854x over previous
//
#include <hip/hip_runtime.h>
#include <cstdint>
#include <cstddef>

#define XDIM 128
#define HDIM 1024
#define ORS 8192   /* out/input row stride = T*XD */

typedef __attribute__((ext_vector_type(8))) short short8;
typedef __attribute__((ext_vector_type(4))) float f32x4;

static const size_t GSTRIDE = (size_t)36 * 64 * 64 * 8;  // shorts per gate group
static const size_t EPACK   = 4 * GSTRIDE;               // shorts per enc/dec pack

__device__ __forceinline__ unsigned short f2bf(float f) {
  union { float f; unsigned u; } c; c.f = f;
  unsigned u = c.u + (0x7fffu + ((c.u >> 16) & 1u));  // RNE; finite inputs
  return (unsigned short)(u >> 16);
}
__device__ __forceinline__ float sigm_(float x) { return 1.f / (1.f + __expf(-x)); }
__device__ __forceinline__ float tanh_(float x) { return 2.f / (1.f + __expf(-2.f * x)) - 1.f; }

__device__ __forceinline__ short8 cvt8(float4 a, float4 b) {
  short8 o;
  o[0] = (short)f2bf(a.x); o[1] = (short)f2bf(a.y); o[2] = (short)f2bf(a.z); o[3] = (short)f2bf(a.w);
  o[4] = (short)f2bf(b.x); o[5] = (short)f2bf(b.y); o[6] = (short)f2bf(b.z); o[7] = (short)f2bf(b.w);
  return o;
}

// ---------------- prep kernels ----------------
__global__ __launch_bounds__(256) void pack_gates(
    const float* __restrict__ eWih, const float* __restrict__ eWhh,
    const float* __restrict__ dWih, const float* __restrict__ dWhh,
    short* __restrict__ Bg)
{
  unsigned t = blockIdx.x * 256u + threadIdx.x;   // 2*4*36*64*64 = 1,179,648
  unsigned l  = t & 63u; t >>= 6;
  unsigned nf = t & 63u; t >>= 6;
  unsigned ks = t % 36u; t /= 36u;
  unsigned g  = t & 3u;  t >>= 2;
  if (t >= 2u) return;
  if ((g == 2u && ks >= 4u) || (g == 3u && ks < 4u)) return;
  const float* Wih = t ? dWih : eWih;
  const float* Whh = t ? dWhh : eWhh;
  int k = (int)(ks * 32u + (l >> 4) * 8u);
  int n = (int)(nf * 16u + (l & 15u));
  const float* src;
  if (g == 3u)      src = Whh + (size_t)(2048 + n) * HDIM + (k - XDIM);
  else if (g == 2u) src = Wih + (size_t)(2048 + n) * XDIM + k;
  else if (ks < 4u) src = Wih + (size_t)(g * HDIM + n) * XDIM + k;
  else              src = Whh + (size_t)(g * HDIM + n) * HDIM + (k - XDIM);
  float4 a = *(const float4*)src;
  float4 b = *(const float4*)(src + 4);
  size_t off = ((((size_t)t * 4u + g) * 36u + ks) * 64u + nf) * 64u + l;
  *(short8*)(Bg + off * 8u) = cvt8(a, b);
}

__global__ __launch_bounds__(256) void pack_lin(const float* __restrict__ linW,
                                                short* __restrict__ Bl)
{
  unsigned t = blockIdx.x * 256u + threadIdx.x;   // 32*8*64 = 16384
  unsigned l  = t & 63u; t >>= 6;
  unsigned nf = t & 7u;  t >>= 3;
  unsigned ks = t;
  if (ks >= 32u) return;
  int k = (int)(ks * 32u + (l >> 4) * 8u);
  int n = (int)(nf * 16u + (l & 15u));
  const float* src = linW + (size_t)n * HDIM + k;
  float4 a = *(const float4*)src;
  float4 b = *(const float4*)(src + 4);
  *(short8*)(Bl + (((size_t)ks * 8u + nf) * 64u + l) * 8u) = cvt8(a, b);
}

__global__ __launch_bounds__(256) void pack_bias(
    const float* __restrict__ eIh, const float* __restrict__ eHh,
    const float* __restrict__ dIh, const float* __restrict__ dHh,
    float* __restrict__ bias)  // [2][4][1024]
{
  unsigned t = blockIdx.x * 256u + threadIdx.x;
  if (t >= 8192u) return;
  unsigned n = t & 1023u, g = (t >> 10) & 3u, e = t >> 12;
  const float* bih = e ? dIh : eIh;
  const float* bhh = e ? dHh : eHh;
  float v;
  if (g == 0u)      v = bih[n] + bhh[n];
  else if (g == 1u) v = bih[HDIM + n] + bhh[HDIM + n];
  else if (g == 2u) v = bih[2 * HDIM + n];
  else              v = bhh[2 * HDIM + n];
  bias[t] = v;
}

// enc input -> frag-major bf16: Xe[i][ks4][lq4][row256][8]
__global__ __launch_bounds__(256) void pack_x(const float* __restrict__ in,
                                              unsigned short* __restrict__ Xe)
{
  unsigned t = blockIdx.x * 256u + threadIdx.x;   // 64*4*4*256 = 262,144
  unsigned row = t & 255u; t >>= 8;
  unsigned lq  = t & 3u;   t >>= 2;
  unsigned ks  = t & 3u;   t >>= 2;
  unsigned i   = t;
  if (i >= 64u) return;
  const float* src = in + (size_t)row * ORS + i * 128u + ks * 32u + lq * 8u;
  float4 a = *(const float4*)src;
  float4 b = *(const float4*)(src + 4);
  *(short8*)(Xe + ((((size_t)i * 4u + ks) * 4u + lq) * 256u + row) * 8u) = cvt8(a, b);
}

// ---------------- fused cell (+proj) kernel ----------------
struct CellArgs {
  const unsigned short* xfrag;   // x frag-major (4 ks) or null
  const unsigned short* afrag;   // An[i] frag-major (32 ks) or null
  const unsigned short* Bg;      // gates pack (enc or dec)
  const float* bias4;
  const float* hpA; const float* hpB; float spA, spB;   // epilogue h_prev combine
  float* hout;                                          // Hf32[i]
  float nsA, nsB; const float* nskip; unsigned short* anext;   // An[i+1]
  float qsA, qsB; const float* qskip; unsigned short* pnext;   // Pn primary
  float q2sA, q2sB; const float* q2skip; unsigned short* p2next; // Pn secondary (dec4)
  const unsigned short* pfrag;   // proj A frag-major (32 ks) or null
  const unsigned short* Blin;
  const float* linb;
  float* pout;                   // out + i*128
  unsigned short* pxout;         // XbfD slot
  int gatesBlocks;
};

#define MFMA(a,b,c) __builtin_amdgcn_mfma_f32_16x16x32_bf16((a),(b),(c),0,0,0)

__global__ __launch_bounds__(512) void rae_cell(CellArgs P) {
  const int tid  = threadIdx.x;
  const int lane = tid & 63;
  const int wave = tid >> 6;
  const int l15  = lane & 15, lq = lane >> 4;
  const int wm = wave & 1, wn = (wave >> 1) & 1, kh = wave >> 2;
  const int w01 = wm * 2 + wn;
  const int bid  = blockIdx.x;
  __shared__ f32x4 red[4][4][64];   // 16 KiB

  if (bid < P.gatesBlocks) {
    const int mt = bid >> 5, ns = bid & 31;     // bid%8 == ns%8 -> XCD-pinned B slice
    const int nf = ns * 2 + wn;
    const int R0 = mt * 32 + wm * 16;
    const int arow = R0 + l15;
    const int colE = ns * 32 + wn * 16 + l15;

    const f32x4 zero = {0.f, 0.f, 0.f, 0.f};
    f32x4 acc0 = zero, acc1 = zero, acc2 = zero, acc3 = zero;

    float hpAv[4] = {0,0,0,0}, hpBv[4] = {0,0,0,0}, nskv[4] = {0,0,0,0},
          qskv[4] = {0,0,0,0}, q2skv[4] = {0,0,0,0};

    if (kh == 1) {
      // x part: ks 0..3, gates r,z,i_n
      if (P.xfrag) {
#pragma unroll
        for (int ks = 0; ks < 4; ++ks) {
          short8 av = *(const short8*)(P.xfrag + (((size_t)(ks * 4 + lq)) * 256 + arow) * 8);
          const unsigned short* bb = P.Bg + ((size_t)(ks * 64 + nf) * 64 + lane) * 8;
          short8 b0 = *(const short8*)(bb);
          short8 b1 = *(const short8*)(bb + GSTRIDE);
          short8 b2 = *(const short8*)(bb + 2 * GSTRIDE);
          acc0 = MFMA(av, b0, acc0); acc1 = MFMA(av, b1, acc1); acc2 = MFMA(av, b2, acc2);
        }
      }
      // h part upper half: ks 20..35, gates r,z,h_n
      if (P.afrag) {
#pragma unroll
        for (int ks = 20; ks < 36; ++ks) {
          short8 av = *(const short8*)(P.afrag + (((size_t)((ks - 4) * 4 + lq)) * 256 + arow) * 8);
          const unsigned short* bb = P.Bg + ((size_t)(ks * 64 + nf) * 64 + lane) * 8;
          short8 b0 = *(const short8*)(bb);
          short8 b1 = *(const short8*)(bb + GSTRIDE);
          short8 b3 = *(const short8*)(bb + 3 * GSTRIDE);
          acc0 = MFMA(av, b0, acc0); acc1 = MFMA(av, b1, acc1); acc3 = MFMA(av, b3, acc3);
        }
      }
      red[w01][0][lane] = acc0; red[w01][1][lane] = acc1;
      red[w01][2][lane] = acc2; red[w01][3][lane] = acc3;
    } else {
      // epilogue prefetches
#pragma unroll
      for (int q = 0; q < 4; ++q) {
        const size_t o = (size_t)(R0 + lq * 4 + q) * HDIM + colE;
        if (P.spA != 0.f) hpAv[q] = P.hpA[o];
        if (P.spB != 0.f) hpBv[q] = P.hpB[o];
        if (P.anext && P.nsB != 0.f) nskv[q] = P.nskip[o];
        if (P.pnext && P.qsB != 0.f) qskv[q] = P.qskip[o];
        if (P.p2next) q2skv[q] = P.q2skip[o];
      }
      // h part lower half: ks 4..19
      if (P.afrag) {
#pragma unroll
        for (int ks = 4; ks < 20; ++ks) {
          short8 av = *(const short8*)(P.afrag + (((size_t)((ks - 4) * 4 + lq)) * 256 + arow) * 8);
          const unsigned short* bb = P.Bg + ((size_t)(ks * 64 + nf) * 64 + lane) * 8;
          short8 b0 = *(const short8*)(bb);
          short8 b1 = *(const short8*)(bb + GSTRIDE);
          short8 b3 = *(const short8*)(bb + 3 * GSTRIDE);
          acc0 = MFMA(av, b0, acc0); acc1 = MFMA(av, b1, acc1); acc3 = MFMA(av, b3, acc3);
        }
      }
    }
    __syncthreads();
    if (kh == 1) return;

    acc0 += red[w01][0][lane]; acc1 += red[w01][1][lane];
    acc2 += red[w01][2][lane]; acc3 += red[w01][3][lane];

    const float br = P.bias4[colE],            bz = P.bias4[HDIM + colE];
    const float bi = P.bias4[2 * HDIM + colE], bh = P.bias4[3 * HDIM + colE];
    const int fa = (colE >> 3) * 2048 + (colE & 7);
#pragma unroll
    for (int q = 0; q < 4; ++q) {
      const int row = R0 + lq * 4 + q;
      const float r  = sigm_(acc0[q] + br);
      const float z  = sigm_(acc1[q] + bz);
      const float nv = tanh_(acc2[q] + bi + r * (acc3[q] + bh));
      const float hp = P.spA * hpAv[q] + P.spB * hpBv[q];
      const float h  = (1.f - z) * nv + z * hp;
      P.hout[(size_t)row * HDIM + colE] = h;
      if (P.anext)  P.anext[fa + row * 8]  = f2bf(P.nsA * h + P.nsB * nskv[q]);
      if (P.pnext)  P.pnext[fa + row * 8]  = f2bf(P.qsA * h + P.qsB * qskv[q]);
      if (P.p2next) P.p2next[fa + row * 8] = f2bf(P.q2sA * h + P.q2sB * q2skv[q]);
    }
  } else {
    // ---- proj: out = Pn @ linW^T + linb ; 8 blocks ----
    const int pb = bid - P.gatesBlocks;
    const int mt = pb >> 1, nt = pb & 1;
    const int arow0 = mt * 64 + wm * 32 + l15;
    const int nfb = nt * 4 + wn * 2;
    const f32x4 zero = {0.f, 0.f, 0.f, 0.f};
    f32x4 a00 = zero, a01 = zero, a10 = zero, a11 = zero;  // [fm][nn]
    const int ksA = kh * 16, ksB = ksA + 16;
#pragma unroll
    for (int ks0 = 0; ks0 < 16; ++ks0) {
      const int ks = ksA + ks0; (void)ksB;
      short8 av0 = *(const short8*)(P.pfrag + (((size_t)(ks * 4 + lq)) * 256 + arow0) * 8);
      short8 av1 = *(const short8*)(P.pfrag + (((size_t)(ks * 4 + lq)) * 256 + arow0 + 16) * 8);
      const unsigned short* bb = P.Blin + ((size_t)(ks * 8 + nfb) * 64 + lane) * 8;
      short8 b0 = *(const short8*)(bb);
      short8 b1 = *(const short8*)(bb + 64 * 8);
      a00 = MFMA(av0, b0, a00); a01 = MFMA(av0, b1, a01);
      a10 = MFMA(av1, b0, a10); a11 = MFMA(av1, b1, a11);
    }
    if (kh == 1) {
      red[w01][0][lane] = a00; red[w01][1][lane] = a01;
      red[w01][2][lane] = a10; red[w01][3][lane] = a11;
    }
    __syncthreads();
    if (kh == 1) return;
    a00 += red[w01][0][lane]; a01 += red[w01][1][lane];
    a10 += red[w01][2][lane]; a11 += red[w01][3][lane];
    f32x4 accs[2][2] = {{a00, a01}, {a10, a11}};
#pragma unroll
    for (int fm = 0; fm < 2; ++fm) {
#pragma unroll
      for (int nn = 0; nn < 2; ++nn) {
        const int col = nt * 64 + wn * 32 + nn * 16 + l15;
        const float lb = P.linb[col];
        const int fx = (col >> 3) * 2048 + (col & 7);
#pragma unroll
        for (int q = 0; q < 4; ++q) {
          const int row = mt * 64 + wm * 32 + fm * 16 + lq * 4 + q;
          const float v = accs[fm][nn][q] + lb;
          P.pout[(size_t)row * ORS + col] = v;
          P.pxout[fx + row * 8] = f2bf(v);
        }
      }
    }
  }
}

// ---------------- host: numpy-legacy MT19937 mask replication ----------------
static void compute_masks(float ew[64][2], float dw[64][2]) {
  unsigned mt[624];
  mt[0] = 0u;
  for (int i = 1; i < 624; ++i)
    mt[i] = 1812433253u * (mt[i - 1] ^ (mt[i - 1] >> 30)) + (unsigned)i;
  int mti = 624;
  auto gen = [&]() -> unsigned {
    if (mti >= 624) {
      for (int i = 0; i < 624; ++i) {
        unsigned y = (mt[i] & 0x80000000u) | (mt[(i + 1) % 624] & 0x7fffffffu);
        unsigned v = mt[(i + 397) % 624] ^ (y >> 1);
        mt[i] = (y & 1u) ? (v ^ 0x9908b0dfu) : v;
      }
      mti = 0;
    }
    unsigned y = mt[mti++];
    y ^= y >> 11; y ^= (y << 7) & 0x9d2c5680u; y ^= (y << 15) & 0xefc60000u; y ^= y >> 18;
    return y;
  };
  auto rbit = [&]() -> int { return (int)(gen() & 1u); };
  for (int t = 0; t < 64; ++t) {
    int w1 = rbit(); int w2 = (w1 == 0) ? 1 : rbit();
    ew[t][0] = (float)w1; ew[t][1] = (float)w2;
  }
  for (int t = 0; t < 64; ++t) {
    int w1 = rbit(); int w2 = (w1 == 0) ? 1 : rbit();
    dw[t][0] = (float)w1; dw[t][1] = (float)w2;
  }
}

extern "C" void kernel_launch(void* const* d_in, const int* in_sizes, int n_in,
                              void* d_out, int out_size, void* d_ws, size_t ws_size,
                              hipStream_t stream)
{
  const float* input = (const float*)d_in[0];
  const float* eWih = (const float*)d_in[1];
  const float* eWhh = (const float*)d_in[2];
  const float* eBih = (const float*)d_in[3];
  const float* eBhh = (const float*)d_in[4];
  const float* dWih = (const float*)d_in[5];
  const float* dWhh = (const float*)d_in[6];
  const float* dBih = (const float*)d_in[7];
  const float* dBhh = (const float*)d_in[8];
  const float* linW = (const float*)d_in[9];
  const float* linb = (const float*)d_in[10];
  float* out = (float*)d_out;

  // workspace layout (bytes)
  if (ws_size < 44597248u) return;
  char* ws = (char*)d_ws;
  short* BgE = (short*)ws;                               // 9,437,184
  short* BgD = BgE + EPACK;                              // 9,437,184
  short* Blin = (short*)(ws + 18874368u);                //   262,144
  float* bias = (float*)(ws + 19136512u);                //    32,768
  float* hring = (float*)(ws + 19169280u);               // 16,777,216
  unsigned short* Xe  = (unsigned short*)(ws + 35946496u); // 4,194,304
  unsigned short* AnB = (unsigned short*)(ws + 40140800u); // 2,097,152 (4 slots)
  unsigned short* PnB = (unsigned short*)(ws + 42237952u); // 2,097,152 (4 slots)
  unsigned short* XdB = (unsigned short*)(ws + 44335104u); //   262,144 (4 slots)

  float ew[64][2], dw[64][2];
  compute_masks(ew, dw);

  pack_gates<<<4608, 256, 0, stream>>>(eWih, eWhh, dWih, dWhh, BgE);
  pack_lin<<<64, 256, 0, stream>>>(linW, Blin);
  pack_bias<<<32, 256, 0, stream>>>(eBih, eBhh, dBih, dBhh, bias);
  pack_x<<<1024, 256, 0, stream>>>(input, Xe);

  auto Hf = [&](int s) -> float* { return hring + (size_t)(s & 15) * (256 * HDIM); };
  auto An = [&](int g) -> unsigned short* { return AnB + (size_t)(g & 3) * 262144u; };
  auto Pn = [&](int g) -> unsigned short* { return PnB + (size_t)(g & 3) * 262144u; };
  auto Xd = [&](int g) -> unsigned short* { return XdB + (size_t)(g & 3) * 32768u; };

  // ---- encoder ----
  for (int i = 0; i < 64; ++i) {
    CellArgs c = {};
    c.Bg = (const unsigned short*)BgE; c.bias4 = bias; c.hout = Hf(i);
    c.xfrag = Xe + (size_t)i * 32768u;
    c.afrag = (i >= 1) ? An(i) : nullptr;
    c.hpA = Hf(i - 1); c.spA = i ? ew[i][0] : 0.f;
    if (i == 3)       { c.hpB = Hf(1);      c.spB = ew[i][1]; }
    else if (i == 4)  { c.hpB = Hf(3);      c.spB = ew[i][1]; }
    else if (i >= 10) { c.hpB = Hf(i - 10); c.spB = ew[i][1]; }
    else              { c.hpB = Hf(0);      c.spB = 0.f; }
    if (i < 63) {
      int n = i + 1;
      c.anext = An(n); c.nskip = Hf(0); c.nsB = 0.f;
      if (n == 4) { c.nsA = ew[4][0] + ew[4][1]; }   // skip source IS h_new (h3)
      else {
        c.nsA = ew[n][0];
        if (n == 3)       { c.nsB = ew[3][1]; c.nskip = Hf(1); }
        else if (n >= 10) { c.nsB = ew[n][1]; c.nskip = Hf(n - 10); }
      }
    } else {  // enc63 -> An[dec0], Pn[0]
      c.anext = An(64); c.nsA = 2.f * dw[0][0]; c.nsB = 0.f; c.nskip = Hf(0);
      c.pnext = Pn(0);  c.qsA = 2.f; c.qsB = 0.f; c.qskip = Hf(0);
    }
    c.gatesBlocks = 256;
    rae_cell<<<256, 512, 0, stream>>>(c);
  }

  // ---- decoder ----
  for (int i = 0; i < 64; ++i) {
    CellArgs c = {};
    c.Bg = (const unsigned short*)BgD; c.bias4 = bias + 4096; c.hout = Hf(i);
    c.xfrag = i ? Xd(i - 1) : nullptr;
    c.afrag = An(64 + i);
    c.hpA = i ? Hf(i - 1) : Hf(15);
    c.spA = i ? dw[i][0] : 2.f * dw[0][0];
    if (i == 3)       { c.hpB = Hf(1);      c.spB = dw[i][1]; }
    else if (i == 4)  { c.hpB = Hf(3);      c.spB = dw[i][1]; }
    else if (i >= 10) { c.hpB = Hf(i - 10); c.spB = dw[i][1]; }
    else              { c.hpB = Hf(0);      c.spB = 0.f; }
    if (i < 63) {
      int n = i + 1;
      c.anext = An(64 + n); c.nskip = Hf(0); c.nsB = 0.f;
      if (n == 4) { c.nsA = dw[4][0] + dw[4][1]; }
      else {
        c.nsA = dw[n][0];
        if (n == 3)       { c.nsB = dw[3][1]; c.nskip = Hf(1); }
        else if (n >= 10) { c.nsB = dw[n][1]; c.nskip = Hf(n - 10); }
      }
    }
    // Pn producer
    c.qskip = Hf(0); c.q2skip = Hf(0);
    if (i == 2)      { c.pnext = Pn(3); c.qsA = 2.f; c.qsB = 0.f; }       // proj3 = 2*h2
    else if (i == 3) { /* Pn[4] deferred to dec4 */ }
    else if (i == 4) { c.pnext = Pn(5); c.qsA = 1.f; c.qsB = 0.f;         // proj5 = h4
                       c.p2next = Pn(4); c.q2sA = 1.f; c.q2sB = 1.f; c.q2skip = Hf(3); } // proj4 = h3+h4
    else if (i < 63) {
      int n = i + 1;
      c.pnext = Pn(n); c.qsA = 1.f; c.qsB = 0.f;
      if (n == 2)       { c.qsB = 1.f; c.qskip = Hf(0); }
      else if (n >= 10) { c.qsB = 1.f; c.qskip = Hf(n - 10); }
    }
    // proj consumer set for this launch
    int grid = 256;
    if (i != 4) {
      c.pfrag = Pn(i); c.pout = out + (size_t)i * XDIM; c.pxout = Xd(i);
      c.Blin = (const unsigned short*)Blin; c.linb = linb;
      grid = 264;
    }
    c.gatesBlocks = 256;
    rae_cell<<<grid, 512, 0, stream>>>(c);

    if (i == 4) {  // standalone proj4 (needs h4 from the launch above)
      CellArgs s = {};
      s.gatesBlocks = 0;
      s.pfrag = Pn(4); s.pout = out + (size_t)4 * XDIM; s.pxout = Xd(4);
      s.Blin = (const unsigned short*)Blin; s.linb = linb;
      rae_cell<<<8, 512, 0, stream>>>(s);
    }
  }
}